// Round 1
// 601.267 us; speedup vs baseline: 1.0997x; 1.0997x over previous
//
#include <hip/hip_runtime.h>

// NodeFeat: out[n,d,c] (c stride 1, d stride 9, n stride 576), c = hop*3 + part
//   hop0: x * {1, rsqrt(deg), sqrt(deg)}
//   hop1: (1/deg) * spmm(hop0)
//   hop2: (1/deg) * spmm(hop1) - hop0
// R2 changes (latency theory):
//   - __shfl(jv,t) -> __builtin_amdgcn_readlane (t is wave-uniform): kills the
//     per-edge ds_bpermute chain; broadcast value lands in SGPR so the gather
//     becomes a saddr-based load.
//   - xs1 repacked as (uint plane: h0|h1<<16) + (ushort plane: h2): 2 gather
//     loads per edge in k_prop2 instead of 3; unpack via shift/mask (no cvt).
//   - edge loops hand-unrolled x4 with loads grouped first (4 independent
//     gather chains in flight).

static inline size_t ws_align(size_t x) { return (x + 255) & ~(size_t)255; }

__device__ inline float bf2f(unsigned short s) {
  return __uint_as_float(((unsigned)s) << 16);
}
__device__ inline unsigned short f2bf(float f) {
  unsigned u = __float_as_uint(f);
  unsigned r = u + 0x7fff + ((u >> 16) & 1);   // round-to-nearest-even
  return (unsigned short)(r >> 16);
}
__device__ inline float bflo(unsigned p) { return __uint_as_float(p << 16); }
__device__ inline float bfhi(unsigned p) { return __uint_as_float(p & 0xffff0000u); }
__device__ inline int rl_i(int v, int t) { return __builtin_amdgcn_readlane(v, t); }
__device__ inline float rl_f(float v, int t) {
  return __uint_as_float(__builtin_amdgcn_readlane(__float_as_uint(v), t));
}

__global__ __launch_bounds__(256) void k_hist(const int* __restrict__ row,
                                              int* __restrict__ counts, int E) {
  int e = blockIdx.x * 256 + threadIdx.x;
  if (e < E) atomicAdd(&counts[row[e]], 1);
}

__global__ __launch_bounds__(1024) void k_blocksum(const int* __restrict__ counts,
                                                   int* __restrict__ partial, int N) {
  __shared__ int wsum[16];
  int t = threadIdx.x;
  int idx = blockIdx.x * 1024 + t;
  int v = (idx < N) ? counts[idx] : 0;
  for (int off = 32; off; off >>= 1) v += __shfl_down(v, off, 64);
  if ((t & 63) == 0) wsum[t >> 6] = v;
  __syncthreads();
  if (t == 0) {
    int s = 0;
#pragma unroll
    for (int k = 0; k < 16; ++k) s += wsum[k];
    partial[blockIdx.x] = s;
  }
}

__global__ void k_scanpartial(const int* __restrict__ partial,
                              int* __restrict__ pscan, int NB) {
  __shared__ int buf[1024];
  int t = threadIdx.x;
  for (int k = t; k < NB; k += blockDim.x) buf[k] = partial[k];
  __syncthreads();
  if (t == 0) {
    int run = 0;
    for (int k = 0; k < NB; ++k) { int v = buf[k]; buf[k] = run; run += v; }
  }
  __syncthreads();
  for (int k = t; k < NB; k += blockDim.x) pscan[k] = buf[k];
}

__global__ __launch_bounds__(1024) void k_scanapply(const int* __restrict__ counts,
    const int* __restrict__ pscan, int* __restrict__ offsets,
    int* __restrict__ cursor, int N) {
  __shared__ int wsum[16];
  int t = threadIdx.x, lane = t & 63, wv = t >> 6;
  int idx = blockIdx.x * 1024 + t;
  int v = (idx < N) ? counts[idx] : 0;
  int x = v;
#pragma unroll
  for (int off = 1; off < 64; off <<= 1) {
    int y = __shfl_up(x, off, 64);
    if (lane >= off) x += y;
  }
  if (lane == 63) wsum[wv] = x;
  __syncthreads();
  if (t == 0) {
    int run = 0;
#pragma unroll
    for (int k = 0; k < 16; ++k) { int s = wsum[k]; wsum[k] = run; run += s; }
  }
  __syncthreads();
  int excl = pscan[blockIdx.x] + wsum[wv] + x - v;
  if (idx < N) { offsets[idx] = excl; cursor[idx] = excl; }
}

__global__ __launch_bounds__(256) void k_scatter(const int* __restrict__ row,
    const int* __restrict__ col, int* __restrict__ cursor,
    int* __restrict__ csr, int E) {
  int e = blockIdx.x * 256 + threadIdx.x;
  if (e < E) {
    int i = row[e];
    int pos = atomicAdd(&cursor[i], 1);
    csr[pos] = col[e];
  }
}
// After k_scatter, cursor[i] == offsets[i] + counts[i]  (used as `ends`).

// x fp32 [N*64] -> bf16 [N*64], 4 elems/thread
__global__ __launch_bounds__(256) void k_cvt(const float4* __restrict__ x,
                                             uint2* __restrict__ xb, int n4) {
  int i = blockIdx.x * 256 + threadIdx.x;
  if (i >= n4) return;
  float4 v = x[i];
  uint2 p;
  p.x = (unsigned)f2bf(v.x) | ((unsigned)f2bf(v.y) << 16);
  p.y = (unsigned)f2bf(v.z) | ((unsigned)f2bf(v.w) << 16);
  xb[i] = p;
}

// hop1: one wave per node, lane = feature. Gathers bf16 x; writes packed xs1:
//   xs1a[b] = h0 | h1<<16  (uint),  xs1b[b] = h2  (ushort)
__global__ __launch_bounds__(256) void k_prop1(const unsigned short* __restrict__ xb,
    const float* __restrict__ deg, const int* __restrict__ offsets,
    const int* __restrict__ ends, const int* __restrict__ csr,
    unsigned* __restrict__ xs1a, unsigned short* __restrict__ xs1b, int N) {
  int w = (blockIdx.x * 256 + threadIdx.x) >> 6;
  int lane = threadIdx.x & 63;
  if (w >= N) return;
  int beg = offsets[w];
  int end = ends[w];
  float s0 = 0.f, s1 = 0.f, s2 = 0.f;
  for (int base = beg; base < end; base += 64) {
    int n = end - base; if (n > 64) n = 64;
    int jv = 0; float rv = 0.f, qv = 0.f;
    if (lane < n) {
      jv = csr[base + lane];
      float dv = deg[jv];
      rv = rsqrtf(dv);
      qv = dv * rv;               // sqrt(dv)
    }
    int t = 0;
    for (; t + 4 <= n; t += 4) {
      int j0 = rl_i(jv, t);
      int j1 = rl_i(jv, t + 1);
      int j2 = rl_i(jv, t + 2);
      int j3 = rl_i(jv, t + 3);
      float v0 = bf2f(xb[(size_t)j0 * 64 + lane]);
      float v1 = bf2f(xb[(size_t)j1 * 64 + lane]);
      float v2 = bf2f(xb[(size_t)j2 * 64 + lane]);
      float v3 = bf2f(xb[(size_t)j3 * 64 + lane]);
      float r0 = rl_f(rv, t),     q0 = rl_f(qv, t);
      float r1 = rl_f(rv, t + 1), q1 = rl_f(qv, t + 1);
      float r2 = rl_f(rv, t + 2), q2 = rl_f(qv, t + 2);
      float r3 = rl_f(rv, t + 3), q3 = rl_f(qv, t + 3);
      s0 += v0 + v1 + v2 + v3;
      s1 += v0 * r0; s1 += v1 * r1; s1 += v2 * r2; s1 += v3 * r3;
      s2 += v0 * q0; s2 += v1 * q1; s2 += v2 * q2; s2 += v3 * q3;
    }
    for (; t < n; ++t) {
      int j   = rl_i(jv, t);
      float r = rl_f(rv, t);
      float q = rl_f(qv, t);
      float v = bf2f(xb[(size_t)j * 64 + lane]);
      s0 += v;
      s1 += v * r;
      s2 += v * q;
    }
  }
  float dr = 1.0f / deg[w];
  size_t b = (size_t)w * 64 + lane;
  xs1a[b] = (unsigned)f2bf(s0 * dr) | ((unsigned)f2bf(s1 * dr) << 16);
  xs1b[b] = f2bf(s2 * dr);
}

// hop2 + full epilogue: gathers packed xs1 (2 loads/edge), recomputes hop0
// from fp32 x, reads own hop1 row, writes ALL 9 floats per (n,d).
__global__ __launch_bounds__(256) void k_prop2(const float* __restrict__ x,
    const float* __restrict__ deg, const int* __restrict__ offsets,
    const int* __restrict__ ends, const int* __restrict__ csr,
    const unsigned* __restrict__ xs1a, const unsigned short* __restrict__ xs1b,
    float* __restrict__ out, int N) {
  int w = (blockIdx.x * 256 + threadIdx.x) >> 6;
  int lane = threadIdx.x & 63;
  if (w >= N) return;
  int beg = offsets[w];
  int end = ends[w];
  float a0 = 0.f, a1 = 0.f, a2 = 0.f;
  for (int base = beg; base < end; base += 64) {
    int n = end - base; if (n > 64) n = 64;
    int jv = 0;
    if (lane < n) jv = csr[base + lane];
    int t = 0;
    for (; t + 4 <= n; t += 4) {
      int j0 = rl_i(jv, t);
      int j1 = rl_i(jv, t + 1);
      int j2 = rl_i(jv, t + 2);
      int j3 = rl_i(jv, t + 3);
      unsigned p0 = xs1a[(size_t)j0 * 64 + lane];
      unsigned p1 = xs1a[(size_t)j1 * 64 + lane];
      unsigned p2 = xs1a[(size_t)j2 * 64 + lane];
      unsigned p3 = xs1a[(size_t)j3 * 64 + lane];
      float c0 = bf2f(xs1b[(size_t)j0 * 64 + lane]);
      float c1 = bf2f(xs1b[(size_t)j1 * 64 + lane]);
      float c2 = bf2f(xs1b[(size_t)j2 * 64 + lane]);
      float c3 = bf2f(xs1b[(size_t)j3 * 64 + lane]);
      a0 += bflo(p0) + bflo(p1) + bflo(p2) + bflo(p3);
      a1 += bfhi(p0) + bfhi(p1) + bfhi(p2) + bfhi(p3);
      a2 += c0 + c1 + c2 + c3;
    }
    for (; t < n; ++t) {
      int j = rl_i(jv, t);
      unsigned p = xs1a[(size_t)j * 64 + lane];
      a0 += bflo(p);
      a1 += bfhi(p);
      a2 += bf2f(xs1b[(size_t)j * 64 + lane]);
    }
  }
  float degi = deg[w];
  float dr = 1.0f / degi;
  float ri = rsqrtf(degi);
  float qi = degi * ri;
  size_t b = (size_t)w * 64 + lane;
  float xv = x[b];
  unsigned pown = xs1a[b];
  float h0 = bflo(pown);
  float h1 = bfhi(pown);
  float h2 = bf2f(xs1b[b]);
  float o0 = xv, o1 = xv * ri, o2 = xv * qi;
  float* op = out + (size_t)w * 576 + (size_t)lane * 9;
  op[0] = o0; op[1] = o1; op[2] = o2;
  op[3] = h0; op[4] = h1; op[5] = h2;
  op[6] = a0 * dr - o0;
  op[7] = a1 * dr - o1;
  op[8] = a2 * dr - o2;
}

extern "C" void kernel_launch(void* const* d_in, const int* in_sizes, int n_in,
                              void* d_out, int out_size, void* d_ws, size_t ws_size,
                              hipStream_t stream) {
  const float* x   = (const float*)d_in[0];
  const float* deg = (const float*)d_in[1];
  const int*   row = (const int*)d_in[2];
  const int*   col = (const int*)d_in[3];
  float* out = (float*)d_out;

  int N = in_sizes[1];       // deg has N elements
  int E = in_sizes[2];       // row has E elements
  int NB = (N + 1023) / 1024;

  char* ws = (char*)d_ws;
  size_t off = 0;
  int* counts  = (int*)(ws + off); off = ws_align(off + (size_t)N * 4);
  int* offsets = (int*)(ws + off); off = ws_align(off + (size_t)N * 4);
  int* cursor  = (int*)(ws + off); off = ws_align(off + (size_t)N * 4);
  int* partial = (int*)(ws + off); off = ws_align(off + (size_t)NB * 4);
  int* pscan   = (int*)(ws + off); off = ws_align(off + (size_t)NB * 4);
  int* csr     = (int*)(ws + off); off = ws_align(off + (size_t)E * 4);
  unsigned short* xb = (unsigned short*)(ws + off); off = ws_align(off + (size_t)N * 64 * 2);
  unsigned* xs1a = (unsigned*)(ws + off); off = ws_align(off + (size_t)N * 64 * 4);
  unsigned short* xs1b = (unsigned short*)(ws + off); off = ws_align(off + (size_t)N * 64 * 2);
  // total ~59 MB; R0 confirmed ws_size >= ~85 MB

  int n4 = N * 16;  // N*64/4 float4 groups
  k_cvt<<<(n4 + 255) / 256, 256, 0, stream>>>((const float4*)x, (uint2*)xb, n4);

  hipMemsetAsync(counts, 0, (size_t)N * 4, stream);
  k_hist<<<(E + 255) / 256, 256, 0, stream>>>(row, counts, E);
  k_blocksum<<<NB, 1024, 0, stream>>>(counts, partial, N);
  k_scanpartial<<<1, 128, 0, stream>>>(partial, pscan, NB);
  k_scanapply<<<NB, 1024, 0, stream>>>(counts, pscan, offsets, cursor, N);
  k_scatter<<<(E + 255) / 256, 256, 0, stream>>>(row, col, cursor, csr, E);

  int hopBlocks = (N + 3) / 4;   // 4 waves/block, 1 wave per node
  k_prop1<<<hopBlocks, 256, 0, stream>>>(xb, deg, offsets, cursor, csr, xs1a, xs1b, N);
  k_prop2<<<hopBlocks, 256, 0, stream>>>(x, deg, offsets, cursor, csr, xs1a, xs1b, out, N);
}